// Round 1
// baseline (106.129 us; speedup 1.0000x reference)
//
#include <hip/hip_runtime.h>
#include <math.h>

// Ising-flip kernel. Layouts:
//   x    (4, 9, 1024, 1024) f32 : channels 0..7 = s, channel 8 = b
//   rand (4, 8, 1024, 1024) f32
//   dropout_rand (1024,1024) f32
//   out  (4, 9, 1024, 1024) f32
// K1: sc[n,y,x] = sum_c s  (sequential order, matching np.sum(axis=1))
// K2: Js = 9-pt cross stencil of sc (exact reference add order, wraparound),
//     p = exp(-2*s*Js*b) via double exp rounded to f32 (bit-exactness of the
//     rand<p comparison is the correctness-critical part), flip sign.

#define NB 4
#define NC 8
#define HH 1024
#define WW 1024
#define PIX (HH * WW)

__global__ __launch_bounds__(256) void sc_kernel(const float* __restrict__ x,
                                                 float* __restrict__ sc) {
    int idx = blockIdx.x * 256 + threadIdx.x;          // 0 .. NB*PIX-1
    int n   = idx >> 20;
    int pix = idx & (PIX - 1);
    const float* base = x + (size_t)n * 9 * PIX + pix;
    float s = base[0];
#pragma unroll
    for (int c = 1; c < NC; ++c) s = s + base[(size_t)c * PIX];
    sc[idx] = s;
}

__global__ __launch_bounds__(256) void ising_kernel(const float* __restrict__ x,
                                                    const float* __restrict__ rnd,
                                                    const float* __restrict__ dr,
                                                    const float* __restrict__ sc,
                                                    float* __restrict__ out) {
    int idx = blockIdx.x * 256 + threadIdx.x;
    int n   = idx >> 20;
    int pix = idx & (PIX - 1);
    int y   = pix >> 10;
    int xc  = pix & (WW - 1);

    const float* scn = sc + (size_t)n * PIX;
    int ym1 = (y - 1) & (HH - 1);
    int yp1 = (y + 1) & (HH - 1);
    int ym2 = (y - 2) & (HH - 1);
    int yp2 = (y + 2) & (HH - 1);
    int xm1 = (xc - 1) & (WW - 1);
    int xp1 = (xc + 1) & (WW - 1);
    int xm2 = (xc - 2) & (WW - 1);
    int xp2 = (xc + 2) & (WW - 1);

    int row = y << 10;
    // EXACT reference accumulation order:
    // Js = sc; +roll(y,1); +roll(y,-1); +roll(x,1); +roll(x,-1);
    //          +roll(y,2); +roll(y,-2); +roll(x,2); +roll(x,-2)
    float Js = scn[row + xc];
    Js = Js + scn[(ym1 << 10) + xc];
    Js = Js + scn[(yp1 << 10) + xc];
    Js = Js + scn[row + xm1];
    Js = Js + scn[row + xp1];
    Js = Js + scn[(ym2 << 10) + xc];
    Js = Js + scn[(yp2 << 10) + xc];
    Js = Js + scn[row + xm2];
    Js = Js + scn[row + xp2];

    const float b  = x[((size_t)n * 9 + NC) * PIX + pix];
    const bool  dm = dr[pix] > 0.5f;

    const float* xs = x   + (size_t)n * 9  * PIX + pix;
    const float* rs = rnd + (size_t)n * NC * PIX + pix;
    float*       os = out + (size_t)n * 9  * PIX + pix;

#pragma unroll
    for (int c = 0; c < NC; ++c) {
        float s = xs[(size_t)c * PIX];
        float r = rs[(size_t)c * PIX];
        float de = (2.0f * s) * Js;            // fl(fl(2s) * Js), 2s exact
        float p = 1.0f;
        if (de > 0.0f) {
            float arg = (-de) * b;             // fl(-de * b), negation exact
            p = (float)exp((double)arg);       // ~correctly-rounded f32 exp
        }
        bool cond = (r < p) && dm;
        os[(size_t)c * PIX] = cond ? -s : s;
    }
    os[(size_t)NC * PIX] = b;
}

extern "C" void kernel_launch(void* const* d_in, const int* in_sizes, int n_in,
                              void* d_out, int out_size, void* d_ws, size_t ws_size,
                              hipStream_t stream) {
    const float* x   = (const float*)d_in[0];
    const float* rnd = (const float*)d_in[1];
    const float* dr  = (const float*)d_in[2];
    float* out = (float*)d_out;
    float* sc  = (float*)d_ws;                 // needs NB*PIX*4 = 16 MiB

    const int total  = NB * PIX;
    const int blocks = total / 256;
    sc_kernel<<<blocks, 256, 0, stream>>>(x, sc);
    ising_kernel<<<blocks, 256, 0, stream>>>(x, rnd, dr, sc, out);
}